// Round 13
// baseline (275.712 us; speedup 1.0000x reference)
//
#include <hip/hip_runtime.h>
#include <hip/hip_bf16.h>
#include <stdint.h>

typedef __bf16 bf16_t;
typedef __bf16 bf16x8 __attribute__((ext_vector_type(8)));
typedef __bf16 bf16x4 __attribute__((ext_vector_type(4)));
typedef float f32x4 __attribute__((ext_vector_type(4)));

#define AS1 __attribute__((address_space(1)))
#define AS3 __attribute__((address_space(3)))

static __device__ __forceinline__ void gload_lds16(const void* g, void* l) {
  __builtin_amdgcn_global_load_lds((const AS1 void*)g, (AS3 void*)l, 16, 0, 0);
}

// v_cvt_pk_bf16_f32: dst.lo = bf16(lo), dst.hi = bf16(hi)
static __device__ __forceinline__ uint32_t cvt_pk(float lo, float hi) {
  uint32_t r;
  asm("v_cvt_pk_bf16_f32 %0, %1, %2" : "=v"(r) : "v"(lo), "v"(hi));
  return r;
}

// ---------------- fp32 -> bf16 convert (vectorized x4) ----------------
__global__ void cvt_f32_bf16(const float* __restrict__ in, bf16_t* __restrict__ out, int n4) {
  int i = blockIdx.x * blockDim.x + threadIdx.x;
  if (i >= n4) return;
  float4 v = ((const float4*)in)[i];
  bf16x4 o;
  o[0] = (bf16_t)v.x; o[1] = (bf16_t)v.y; o[2] = (bf16_t)v.z; o[3] = (bf16_t)v.w;
  *(bf16x4*)(out + (size_t)i * 4) = o;
}

// ---------------- GEMM C = A(MxK) * B(NxK)^T, bf16 in, fp32 acc ----------------
// MODE 0: qkv epilogue. q: scaled 0.125, (bh,t,d). k: (bh,t,d).
//         v: TILE-BLOCKED (bh, kt[32], d[64], ksigma[64]); sigma: k bits
//         [f|u|l4|c] -> pos bits [f|l4|u|c] so flash PV B-op is lane-local.
// MODE 1: proj epilogue (+bias, fp32 row-major out)
template<int MODE>
__global__ __launch_bounds__(256) void gemm_bt(
    const bf16_t* __restrict__ A, const bf16_t* __restrict__ Bw,
    const float* __restrict__ bias, void* __restrict__ Cout,
    int M, int N, int K)
{
  __shared__ bf16_t As[128 * 32];
  __shared__ bf16_t Bs[128 * 32];
  const int tid = threadIdx.x;
  const int wave = tid >> 6, lane = tid & 63;
  const int l15 = lane & 15, l4 = lane >> 4;
  const int m0 = blockIdx.y * 128, n0 = blockIdx.x * 128;
  const int wm = (wave >> 1) * 64, wn = (wave & 1) * 64;
  f32x4 acc[4][4] = {};

  const int r = tid >> 2;
  const int cb = (tid & 3) * 16;
  const char* gA0 = (const char*)(A + (size_t)(m0 + r) * K) + cb;
  const char* gA1 = (const char*)(A + (size_t)(m0 + 64 + r) * K) + cb;
  const char* gB0 = (const char*)(Bw + (size_t)(n0 + r) * K) + cb;
  const char* gB1 = (const char*)(Bw + (size_t)(n0 + 64 + r) * K) + cb;
  char* lA = (char*)As + tid * 16;
  char* lB = (char*)Bs + tid * 16;

  for (int k0 = 0; k0 < K; k0 += 32) {
    const size_t koff = (size_t)k0 * 2;
    gload_lds16(gA0 + koff, lA);
    gload_lds16(gA1 + koff, lA + 4096);
    gload_lds16(gB0 + koff, lB);
    gload_lds16(gB1 + koff, lB + 4096);
    __syncthreads();
    bf16x8 af[4], bfr[4];
#pragma unroll
    for (int mt = 0; mt < 4; ++mt)
      af[mt] = *(const bf16x8*)&As[(wm + mt * 16 + l15) * 32 + l4 * 8];
#pragma unroll
    for (int nt = 0; nt < 4; ++nt)
      bfr[nt] = *(const bf16x8*)&Bs[(wn + nt * 16 + l15) * 32 + l4 * 8];
#pragma unroll
    for (int mt = 0; mt < 4; ++mt)
#pragma unroll
      for (int nt = 0; nt < 4; ++nt)
        acc[mt][nt] = __builtin_amdgcn_mfma_f32_16x16x32_bf16(af[mt], bfr[nt], acc[mt][nt], 0, 0, 0);
    __syncthreads();
  }

  if (MODE == 0) {
    bf16_t* qkv = (bf16_t*)Cout;
#pragma unroll
    for (int mt = 0; mt < 4; ++mt) {
#pragma unroll
      for (int nt = 0; nt < 4; ++nt) {
        const int col = n0 + wn + nt * 16 + l15;
        const float bv = bias[col];
        const int which = col >> 10;
        const int c = col & 1023;
        const int head = c >> 6, d = c & 63;
#pragma unroll
        for (int i = 0; i < 4; ++i) {
          const int row = m0 + wm + mt * 16 + l4 * 4 + i;
          const int bb = row >> 11, t = row & 2047;
          const int bh2 = bb * 16 + head;
          float v = acc[mt][nt][i] + bv;
          size_t idx;
          if (which == 0) {
            v *= 0.125f;
            idx = ((size_t)(bh2 * 2048 + t) << 6) + d;
          } else if (which == 1) {
            idx = 8388608 + ((size_t)(bh2 * 2048 + t) << 6) + d;
          } else {
            const int ko = t & 63;
            const int pos = (ko & 0x20) | ((ko & 0x0C) << 1) | ((ko & 0x10) >> 2) | (ko & 3);
            idx = 16777216 + (size_t)bh2 * 131072 + ((size_t)(t >> 6) << 12) + d * 64 + pos;
          }
          qkv[idx] = (bf16_t)v;
        }
      }
    }
  } else {
    float* C = (float*)Cout;
#pragma unroll
    for (int mt = 0; mt < 4; ++mt) {
#pragma unroll
      for (int nt = 0; nt < 4; ++nt) {
        const int col = n0 + wn + nt * 16 + l15;
        const float bv = bias[col];
#pragma unroll
        for (int i = 0; i < 4; ++i) {
          const int row = m0 + wm + mt * 16 + l4 * 4 + i;
          C[(size_t)row * N + col] = acc[mt][nt][i] + bv;
        }
      }
    }
  }
}

// ---------------- one 16-q-row half-step (swapped-operand, in-lane SM) ----
static __device__ __forceinline__ void half_step(
    const bf16x8& kA0, const bf16x8& kB0, const bf16x8& kA1, const bf16x8& kB1,
    const bf16x8& kA2, const bf16x8& kB2, const bf16x8& kA3, const bf16x8& kB3,
    const bf16x8& vA0, const bf16x8& vB0, const bf16x8& vA1, const bf16x8& vB1,
    const bf16x8& vA2, const bf16x8& vB2, const bf16x8& vA3, const bf16x8& vB3,
    const bf16x8 aq0, const bf16x8 aq1,
    float& m_i, float& l_i,
    f32x4& o0, f32x4& o1, f32x4& o2, f32x4& o3,
    const bool diag, const int qb, const int kb)
{
  f32x4 s0 = {}, s1 = {}, s2 = {}, s3 = {};
  s0 = __builtin_amdgcn_mfma_f32_16x16x32_bf16(kA0, aq0, s0, 0, 0, 0);
  s0 = __builtin_amdgcn_mfma_f32_16x16x32_bf16(kB0, aq1, s0, 0, 0, 0);
  s1 = __builtin_amdgcn_mfma_f32_16x16x32_bf16(kA1, aq0, s1, 0, 0, 0);
  s1 = __builtin_amdgcn_mfma_f32_16x16x32_bf16(kB1, aq1, s1, 0, 0, 0);
  s2 = __builtin_amdgcn_mfma_f32_16x16x32_bf16(kA2, aq0, s2, 0, 0, 0);
  s2 = __builtin_amdgcn_mfma_f32_16x16x32_bf16(kB2, aq1, s2, 0, 0, 0);
  s3 = __builtin_amdgcn_mfma_f32_16x16x32_bf16(kA3, aq0, s3, 0, 0, 0);
  s3 = __builtin_amdgcn_mfma_f32_16x16x32_bf16(kB3, aq1, s3, 0, 0, 0);

  if (diag) {
#pragma unroll
    for (int i = 0; i < 4; ++i) {
      if (kb + i > qb)      s0[i] = -1e30f;
      if (16 + kb + i > qb) s1[i] = -1e30f;
      if (32 + kb + i > qb) s2[i] = -1e30f;
      if (48 + kb + i > qb) s3[i] = -1e30f;
    }
  }

  float pm = fmaxf(fmaxf(fmaxf(s0[0], s0[1]), fmaxf(s0[2], s0[3])),
                   fmaxf(fmaxf(s1[0], s1[1]), fmaxf(s1[2], s1[3])));
  pm = fmaxf(pm, fmaxf(fmaxf(fmaxf(s2[0], s2[1]), fmaxf(s2[2], s2[3])),
                       fmaxf(fmaxf(s3[0], s3[1]), fmaxf(s3[2], s3[3]))));
  pm = fmaxf(pm, __shfl_xor(pm, 16));
  pm = fmaxf(pm, __shfl_xor(pm, 32));

  // defer-max: skip rescale when the running max barely grows (P <= e^8)
  const bool keep = __all(pm - m_i <= 8.f);
  const float mn = keep ? m_i : fmaxf(m_i, pm);
  const float sc = keep ? 1.f : __expf(m_i - mn);
  m_i = mn;
#pragma unroll
  for (int i = 0; i < 4; ++i) {
    s0[i] = __expf(s0[i] - mn);
    s1[i] = __expf(s1[i] - mn);
    s2[i] = __expf(s2[i] - mn);
    s3[i] = __expf(s3[i] - mn);
  }
  float rs = ((s0[0] + s0[1]) + (s0[2] + s0[3])) + ((s1[0] + s1[1]) + (s1[2] + s1[3]))
           + ((s2[0] + s2[1]) + (s2[2] + s2[3])) + ((s3[0] + s3[1]) + (s3[2] + s3[3]));
  rs += __shfl_xor(rs, 16);
  rs += __shfl_xor(rs, 32);
  if (keep) {
    l_i = l_i + rs;
  } else {
    l_i = l_i * sc + rs;
    o0 *= sc; o1 *= sc; o2 *= sc; o3 *= sc;
  }

  union { uint32_t u[4]; bf16x8 v; } B0, B1;
  B0.u[0] = cvt_pk(s0[0], s0[1]); B0.u[1] = cvt_pk(s0[2], s0[3]);
  B0.u[2] = cvt_pk(s1[0], s1[1]); B0.u[3] = cvt_pk(s1[2], s1[3]);
  B1.u[0] = cvt_pk(s2[0], s2[1]); B1.u[1] = cvt_pk(s2[2], s2[3]);
  B1.u[2] = cvt_pk(s3[0], s3[1]); B1.u[3] = cvt_pk(s3[2], s3[3]);

  o0 = __builtin_amdgcn_mfma_f32_16x16x32_bf16(vA0, B0.v, o0, 0, 0, 0);
  o0 = __builtin_amdgcn_mfma_f32_16x16x32_bf16(vB0, B1.v, o0, 0, 0, 0);
  o1 = __builtin_amdgcn_mfma_f32_16x16x32_bf16(vA1, B0.v, o1, 0, 0, 0);
  o1 = __builtin_amdgcn_mfma_f32_16x16x32_bf16(vB1, B1.v, o1, 0, 0, 0);
  o2 = __builtin_amdgcn_mfma_f32_16x16x32_bf16(vA2, B0.v, o2, 0, 0, 0);
  o2 = __builtin_amdgcn_mfma_f32_16x16x32_bf16(vB2, B1.v, o2, 0, 0, 0);
  o3 = __builtin_amdgcn_mfma_f32_16x16x32_bf16(vA3, B0.v, o3, 0, 0, 0);
  o3 = __builtin_amdgcn_mfma_f32_16x16x32_bf16(vB3, B1.v, o3, 0, 0, 0);
}

// load one k-tile's 16 fragments into register set with prefix P (x or y)
#define LOAD_SET(P, kq, vq) \
  P##kA0 = *(const bf16x8*)((kq) + 0);        P##kB0 = *(const bf16x8*)((kq) + 32);        \
  P##kA1 = *(const bf16x8*)((kq) + 1024);     P##kB1 = *(const bf16x8*)((kq) + 1024 + 32); \
  P##kA2 = *(const bf16x8*)((kq) + 2048);     P##kB2 = *(const bf16x8*)((kq) + 2048 + 32); \
  P##kA3 = *(const bf16x8*)((kq) + 3072);     P##kB3 = *(const bf16x8*)((kq) + 3072 + 32); \
  P##vA0 = *(const bf16x8*)((vq) + 0);        P##vB0 = *(const bf16x8*)((vq) + 32);        \
  P##vA1 = *(const bf16x8*)((vq) + 1024);     P##vB1 = *(const bf16x8*)((vq) + 1024 + 32); \
  P##vA2 = *(const bf16x8*)((vq) + 2048);     P##vB2 = *(const bf16x8*)((vq) + 2048 + 32); \
  P##vA3 = *(const bf16x8*)((vq) + 3072);     P##vB3 = *(const bf16x8*)((vq) + 3072 + 32);

#define XSET xkA0,xkB0,xkA1,xkB1,xkA2,xkB2,xkA3,xkB3,xvA0,xvB0,xvA1,xvB1,xvA2,xvB2,xvA3,xvB3
#define YSET ykA0,ykB0,ykA1,ykB1,ykA2,ykB2,ykA3,ykB3,yvA0,yvB0,yvA1,yvB1,yvA2,yvB2,yvA3,yvB3

// ---------------- causal flash attention: 4 free-running waves / block ----
// grid 1024 x 256 threads. Each block = 4 INDEPENDENT waves (no barriers,
// no LDS, no shared state); wave w owns q-group s = 4*g + w (32 rows, two
// 16-row halves, same k-bound, shared K/V fragments, depth-2 register
// prefetch). Packing 4 waves/workgroup keeps workgroup count at 1024 --
// under the HW in-flight-workgroup limit that capped 1-wave grids at ~876
// resident waves (R12: occupancy 10.7% despite VGPR headroom).
__global__ __launch_bounds__(256) void flash_attn(
    const bf16_t* __restrict__ Qg, const bf16_t* __restrict__ Kg,
    const bf16_t* __restrict__ VTg, bf16_t* __restrict__ Y)
{
  const int T = 2048, HS = 64;
  const int flat = blockIdx.x;         // 0..1023
  const int xcd = flat & 7;
  const int rest = flat >> 3;          // 0..127
  const int bh = xcd * 8 + (rest & 7); // 8 heads per XCD -> K/V L2-resident
  const int g = 15 - (rest >> 3);      // 0..15, longest groups first
  const int wave = threadIdx.x >> 6;
  const int s = g * 4 + wave;          // 0..63: this wave's 32-row q-group
  const size_t baseQ = (size_t)bh * T * HS;   // Q,K: (bh, t, d)
  const size_t baseV = (size_t)bh * HS * T;   // V: (bh, kt, d, ksigma) tiles

  const int lane = threadIdx.x & 63;
  const int l15 = lane & 15, l4 = lane >> 4;

  const int bound = s >> 1;                 // last k-tile (same for halves)
  const int qb0 = ((s & 1) << 5) + l15;     // q offset within diag 64-tile
  const int qb1 = qb0 + 16;
  const int kb = l4 * 4;

  // Q fragments: half0 rows 32s+l15, half1 rows 32s+16+l15
  const bf16_t* qr = Qg + baseQ + (size_t)(32 * s + l15) * HS;
  const bf16x8 aq00 = *(const bf16x8*)(qr + l4 * 8);
  const bf16x8 aq01 = *(const bf16x8*)(qr + 32 + l4 * 8);
  const bf16x8 aq10 = *(const bf16x8*)(qr + 16 * HS + l4 * 8);
  const bf16x8 aq11 = *(const bf16x8*)(qr + 16 * HS + 32 + l4 * 8);

  float m0 = -1e30f, l0 = 0.f, m1 = -1e30f, l1 = 0.f;
  f32x4 o00 = {}, o01 = {}, o02 = {}, o03 = {};
  f32x4 o10 = {}, o11 = {}, o12 = {}, o13 = {};

  // per-lane fragment bases (both advance 4096 elems per k-tile)
  const bf16_t* kp = Kg + baseQ + (size_t)l15 * HS + l4 * 8;
  const bf16_t* vp = VTg + baseV + (size_t)l15 * 64 + l4 * 8;

  bf16x8 XSET;
  bf16x8 YSET;

  LOAD_SET(x, kp, vp)

  for (int kt = 0; kt <= bound; kt += 2) {
    // even step: prefetch kt+1 into Y, compute kt from X
    if (kt + 1 <= bound) {
      kp += 4096; vp += 4096;
      LOAD_SET(y, kp, vp)
    }
    {
      const bool dg = (kt == bound);
      half_step(XSET, aq00, aq01, m0, l0, o00, o01, o02, o03, dg, qb0, kb);
      half_step(XSET, aq10, aq11, m1, l1, o10, o11, o12, o13, dg, qb1, kb);
    }
    if (kt + 1 > bound) break;
    // odd step: prefetch kt+2 into X, compute kt+1 from Y
    if (kt + 2 <= bound) {
      kp += 4096; vp += 4096;
      LOAD_SET(x, kp, vp)
    }
    {
      const bool dg = (kt + 1 == bound);
      half_step(YSET, aq00, aq01, m0, l0, o00, o01, o02, o03, dg, qb0, kb);
      half_step(YSET, aq10, aq11, m1, l1, o10, o11, o12, o13, dg, qb1, kb);
    }
  }

  // epilogue: O^T (d = t*16+l4*4+i, q = l15) -> Y (B,T,C) bf16, packed 8B
  const int b = bh >> 4;
  const int h = bh & 15;
  {
    const float il = 1.f / l0;
    const int q = 32 * s + l15;
    bf16_t* yr = Y + ((size_t)(b * T + q)) * 1024 + h * 64 + l4 * 4;
    uint2 w;
    w.x = cvt_pk(o00[0] * il, o00[1] * il); w.y = cvt_pk(o00[2] * il, o00[3] * il);
    *(uint2*)(yr + 0) = w;
    w.x = cvt_pk(o01[0] * il, o01[1] * il); w.y = cvt_pk(o01[2] * il, o01[3] * il);
    *(uint2*)(yr + 16) = w;
    w.x = cvt_pk(o02[0] * il, o02[1] * il); w.y = cvt_pk(o02[2] * il, o02[3] * il);
    *(uint2*)(yr + 32) = w;
    w.x = cvt_pk(o03[0] * il, o03[1] * il); w.y = cvt_pk(o03[2] * il, o03[3] * il);
    *(uint2*)(yr + 48) = w;
  }
  {
    const float il = 1.f / l1;
    const int q = 32 * s + 16 + l15;
    bf16_t* yr = Y + ((size_t)(b * T + q)) * 1024 + h * 64 + l4 * 4;
    uint2 w;
    w.x = cvt_pk(o10[0] * il, o10[1] * il); w.y = cvt_pk(o10[2] * il, o10[3] * il);
    *(uint2*)(yr + 0) = w;
    w.x = cvt_pk(o11[0] * il, o11[1] * il); w.y = cvt_pk(o11[2] * il, o11[3] * il);
    *(uint2*)(yr + 16) = w;
    w.x = cvt_pk(o12[0] * il, o12[1] * il); w.y = cvt_pk(o12[2] * il, o12[3] * il);
    *(uint2*)(yr + 32) = w;
    w.x = cvt_pk(o13[0] * il, o13[1] * il); w.y = cvt_pk(o13[2] * il, o13[3] * il);
    *(uint2*)(yr + 48) = w;
  }
}

// ---------------- launch ----------------
extern "C" void kernel_launch(void* const* d_in, const int* in_sizes, int n_in,
                              void* d_out, int out_size, void* d_ws, size_t ws_size,
                              hipStream_t stream) {
  const float* x      = (const float*)d_in[0];
  const float* w_attn = (const float*)d_in[1];
  const float* b_attn = (const float*)d_in[2];
  const float* w_proj = (const float*)d_in[3];
  const float* b_proj = (const float*)d_in[4];
  float* out = (float*)d_out;

  char* ws = (char*)d_ws;
  bf16_t* xb   = (bf16_t*)(ws);
  bf16_t* wab  = (bf16_t*)(ws + 16777216);
  bf16_t* wpb  = (bf16_t*)(ws + 23068672);
  bf16_t* qkvb = (bf16_t*)(ws + 25165824);   // q | k | vTiles (8M elems each)
  bf16_t* yb   = (bf16_t*)(ws + 75497472);

  cvt_f32_bf16<<<8192, 256, 0, stream>>>(x, xb, 2097152);
  cvt_f32_bf16<<<3072, 256, 0, stream>>>(w_attn, wab, 786432);
  cvt_f32_bf16<<<1024, 256, 0, stream>>>(w_proj, wpb, 262144);

  dim3 g1(24, 64);
  gemm_bt<0><<<g1, 256, 0, stream>>>(xb, wab, b_attn, (void*)qkvb, 8192, 3072, 1024);

  flash_attn<<<1024, 256, 0, stream>>>(qkvb, qkvb + 8388608, qkvb + 16777216, yb);

  dim3 g3(8, 64);
  gemm_bt<1><<<g3, 256, 0, stream>>>(yb, wpb, b_proj, (void*)out, 8192, 1024, 1024);
}

// Round 15
// 260.223 us; speedup vs baseline: 1.0595x; 1.0595x over previous
//
#include <hip/hip_runtime.h>
#include <hip/hip_bf16.h>
#include <stdint.h>

typedef __bf16 bf16_t;
typedef __bf16 bf16x8 __attribute__((ext_vector_type(8)));
typedef __bf16 bf16x4 __attribute__((ext_vector_type(4)));
typedef float f32x4 __attribute__((ext_vector_type(4)));

#define AS1 __attribute__((address_space(1)))
#define AS3 __attribute__((address_space(3)))

static __device__ __forceinline__ void gload_lds16(const void* g, void* l) {
  __builtin_amdgcn_global_load_lds((const AS1 void*)g, (AS3 void*)l, 16, 0, 0);
}

// v_cvt_pk_bf16_f32: dst.lo = bf16(lo), dst.hi = bf16(hi)
static __device__ __forceinline__ uint32_t cvt_pk(float lo, float hi) {
  uint32_t r;
  asm("v_cvt_pk_bf16_f32 %0, %1, %2" : "=v"(r) : "v"(lo), "v"(hi));
  return r;
}

// ---------------- fp32 -> bf16 convert (vectorized x4) ----------------
__global__ void cvt_f32_bf16(const float* __restrict__ in, bf16_t* __restrict__ out, int n4) {
  int i = blockIdx.x * blockDim.x + threadIdx.x;
  if (i >= n4) return;
  float4 v = ((const float4*)in)[i];
  bf16x4 o;
  o[0] = (bf16_t)v.x; o[1] = (bf16_t)v.y; o[2] = (bf16_t)v.z; o[3] = (bf16_t)v.w;
  *(bf16x4*)(out + (size_t)i * 4) = o;
}

// ---------------- GEMM C = A(MxK) * B(NxK)^T, bf16 in, fp32 acc ----------------
// XCD-aware block swizzle (T1): consecutive logical blocks (sharing a 128-row
// A-panel) cluster on one XCD -> panel becomes an L2 hit instead of being
// fetched by 8 XCDs. Requires nwg % 8 == 0 (1536 and 512: both OK).
// MODE 0: qkv epilogue. q: scaled 0.125, (bh,t,d). k: (bh,t,d).
//         v: TILE-BLOCKED (bh, kt[32], d[64], ksigma[64]); sigma: k bits
//         [f|u|l4|c] -> pos bits [f|l4|u|c] so flash PV B-op is lane-local.
// MODE 1: proj epilogue (+bias, fp32 row-major out)
template<int MODE>
__global__ __launch_bounds__(256) void gemm_bt(
    const bf16_t* __restrict__ A, const bf16_t* __restrict__ Bw,
    const float* __restrict__ bias, void* __restrict__ Cout,
    int M, int N, int K)
{
  __shared__ bf16_t As[128 * 32];
  __shared__ bf16_t Bs[128 * 32];
  const int tid = threadIdx.x;
  const int wave = tid >> 6, lane = tid & 63;
  const int l15 = lane & 15, l4 = lane >> 4;
  // XCD swizzle: fid -> nid (bijective, nwg multiple of 8)
  const int nwgx = gridDim.x;
  const int fid = blockIdx.y * nwgx + blockIdx.x;
  const int qq = (nwgx * gridDim.y) >> 3;
  const int nid = (fid & 7) * qq + (fid >> 3);
  const int m0 = (nid / nwgx) * 128, n0 = (nid % nwgx) * 128;
  const int wm = (wave >> 1) * 64, wn = (wave & 1) * 64;
  f32x4 acc[4][4] = {};

  const int r = tid >> 2;
  const int cb = (tid & 3) * 16;
  const char* gA0 = (const char*)(A + (size_t)(m0 + r) * K) + cb;
  const char* gA1 = (const char*)(A + (size_t)(m0 + 64 + r) * K) + cb;
  const char* gB0 = (const char*)(Bw + (size_t)(n0 + r) * K) + cb;
  const char* gB1 = (const char*)(Bw + (size_t)(n0 + 64 + r) * K) + cb;
  char* lA = (char*)As + tid * 16;
  char* lB = (char*)Bs + tid * 16;

  for (int k0 = 0; k0 < K; k0 += 32) {
    const size_t koff = (size_t)k0 * 2;
    gload_lds16(gA0 + koff, lA);
    gload_lds16(gA1 + koff, lA + 4096);
    gload_lds16(gB0 + koff, lB);
    gload_lds16(gB1 + koff, lB + 4096);
    __syncthreads();
    bf16x8 af[4], bfr[4];
#pragma unroll
    for (int mt = 0; mt < 4; ++mt)
      af[mt] = *(const bf16x8*)&As[(wm + mt * 16 + l15) * 32 + l4 * 8];
#pragma unroll
    for (int nt = 0; nt < 4; ++nt)
      bfr[nt] = *(const bf16x8*)&Bs[(wn + nt * 16 + l15) * 32 + l4 * 8];
#pragma unroll
    for (int mt = 0; mt < 4; ++mt)
#pragma unroll
      for (int nt = 0; nt < 4; ++nt)
        acc[mt][nt] = __builtin_amdgcn_mfma_f32_16x16x32_bf16(af[mt], bfr[nt], acc[mt][nt], 0, 0, 0);
    __syncthreads();
  }

  if (MODE == 0) {
    bf16_t* qkv = (bf16_t*)Cout;
#pragma unroll
    for (int mt = 0; mt < 4; ++mt) {
#pragma unroll
      for (int nt = 0; nt < 4; ++nt) {
        const int col = n0 + wn + nt * 16 + l15;
        const float bv = bias[col];
        const int which = col >> 10;
        const int c = col & 1023;
        const int head = c >> 6, d = c & 63;
#pragma unroll
        for (int i = 0; i < 4; ++i) {
          const int row = m0 + wm + mt * 16 + l4 * 4 + i;
          const int bb = row >> 11, t = row & 2047;
          const int bh2 = bb * 16 + head;
          float v = acc[mt][nt][i] + bv;
          size_t idx;
          if (which == 0) {
            v *= 0.125f;
            idx = ((size_t)(bh2 * 2048 + t) << 6) + d;
          } else if (which == 1) {
            idx = 8388608 + ((size_t)(bh2 * 2048 + t) << 6) + d;
          } else {
            const int ko = t & 63;
            const int pos = (ko & 0x20) | ((ko & 0x0C) << 1) | ((ko & 0x10) >> 2) | (ko & 3);
            idx = 16777216 + (size_t)bh2 * 131072 + ((size_t)(t >> 6) << 12) + d * 64 + pos;
          }
          qkv[idx] = (bf16_t)v;
        }
      }
    }
  } else {
    float* C = (float*)Cout;
#pragma unroll
    for (int mt = 0; mt < 4; ++mt) {
#pragma unroll
      for (int nt = 0; nt < 4; ++nt) {
        const int col = n0 + wn + nt * 16 + l15;
        const float bv = bias[col];
#pragma unroll
        for (int i = 0; i < 4; ++i) {
          const int row = m0 + wm + mt * 16 + l4 * 4 + i;
          C[(size_t)row * N + col] = acc[mt][nt][i] + bv;
        }
      }
    }
  }
}

// ---------------- one 16-q-row half-step (swapped-operand, in-lane SM) ----
// Lane holds S[q=l15][k = t*16 + kb + i]. Softmax in-lane, 2 shuffles.
// Defer-max (T13): if wave-wide pm-m <= 8, keep old max, skip O-rescale.
// PV: O^T += mfma(Vfrag, cvt_pk-pack(P)); V sigma-permuted so pack is
// lane-local. All state in named registers.
static __device__ __forceinline__ void half_step(
    const bf16x8& kA0, const bf16x8& kB0, const bf16x8& kA1, const bf16x8& kB1,
    const bf16x8& kA2, const bf16x8& kB2, const bf16x8& kA3, const bf16x8& kB3,
    const bf16x8& vA0, const bf16x8& vB0, const bf16x8& vA1, const bf16x8& vB1,
    const bf16x8& vA2, const bf16x8& vB2, const bf16x8& vA3, const bf16x8& vB3,
    const bf16x8 aq0, const bf16x8 aq1,
    float& m_i, float& l_i,
    f32x4& o0, f32x4& o1, f32x4& o2, f32x4& o3,
    const bool diag, const int qb, const int kb)
{
  f32x4 s0 = {}, s1 = {}, s2 = {}, s3 = {};
  s0 = __builtin_amdgcn_mfma_f32_16x16x32_bf16(kA0, aq0, s0, 0, 0, 0);
  s0 = __builtin_amdgcn_mfma_f32_16x16x32_bf16(kB0, aq1, s0, 0, 0, 0);
  s1 = __builtin_amdgcn_mfma_f32_16x16x32_bf16(kA1, aq0, s1, 0, 0, 0);
  s1 = __builtin_amdgcn_mfma_f32_16x16x32_bf16(kB1, aq1, s1, 0, 0, 0);
  s2 = __builtin_amdgcn_mfma_f32_16x16x32_bf16(kA2, aq0, s2, 0, 0, 0);
  s2 = __builtin_amdgcn_mfma_f32_16x16x32_bf16(kB2, aq1, s2, 0, 0, 0);
  s3 = __builtin_amdgcn_mfma_f32_16x16x32_bf16(kA3, aq0, s3, 0, 0, 0);
  s3 = __builtin_amdgcn_mfma_f32_16x16x32_bf16(kB3, aq1, s3, 0, 0, 0);

  if (diag) {
#pragma unroll
    for (int i = 0; i < 4; ++i) {
      if (kb + i > qb)      s0[i] = -1e30f;
      if (16 + kb + i > qb) s1[i] = -1e30f;
      if (32 + kb + i > qb) s2[i] = -1e30f;
      if (48 + kb + i > qb) s3[i] = -1e30f;
    }
  }

  float pm = fmaxf(fmaxf(fmaxf(s0[0], s0[1]), fmaxf(s0[2], s0[3])),
                   fmaxf(fmaxf(s1[0], s1[1]), fmaxf(s1[2], s1[3])));
  pm = fmaxf(pm, fmaxf(fmaxf(fmaxf(s2[0], s2[1]), fmaxf(s2[2], s2[3])),
                       fmaxf(fmaxf(s3[0], s3[1]), fmaxf(s3[2], s3[3]))));
  pm = fmaxf(pm, __shfl_xor(pm, 16));
  pm = fmaxf(pm, __shfl_xor(pm, 32));

  // defer-max: skip rescale when the running max barely grows (P <= e^8)
  const bool keep = __all(pm - m_i <= 8.f);
  const float mn = keep ? m_i : fmaxf(m_i, pm);
  const float sc = keep ? 1.f : __expf(m_i - mn);
  m_i = mn;
#pragma unroll
  for (int i = 0; i < 4; ++i) {
    s0[i] = __expf(s0[i] - mn);
    s1[i] = __expf(s1[i] - mn);
    s2[i] = __expf(s2[i] - mn);
    s3[i] = __expf(s3[i] - mn);
  }
  float rs = ((s0[0] + s0[1]) + (s0[2] + s0[3])) + ((s1[0] + s1[1]) + (s1[2] + s1[3]))
           + ((s2[0] + s2[1]) + (s2[2] + s2[3])) + ((s3[0] + s3[1]) + (s3[2] + s3[3]));
  rs += __shfl_xor(rs, 16);
  rs += __shfl_xor(rs, 32);
  if (keep) {
    l_i = l_i + rs;
  } else {
    l_i = l_i * sc + rs;
    o0 *= sc; o1 *= sc; o2 *= sc; o3 *= sc;
  }

  union { uint32_t u[4]; bf16x8 v; } B0, B1;
  B0.u[0] = cvt_pk(s0[0], s0[1]); B0.u[1] = cvt_pk(s0[2], s0[3]);
  B0.u[2] = cvt_pk(s1[0], s1[1]); B0.u[3] = cvt_pk(s1[2], s1[3]);
  B1.u[0] = cvt_pk(s2[0], s2[1]); B1.u[1] = cvt_pk(s2[2], s2[3]);
  B1.u[2] = cvt_pk(s3[0], s3[1]); B1.u[3] = cvt_pk(s3[2], s3[3]);

  o0 = __builtin_amdgcn_mfma_f32_16x16x32_bf16(vA0, B0.v, o0, 0, 0, 0);
  o0 = __builtin_amdgcn_mfma_f32_16x16x32_bf16(vB0, B1.v, o0, 0, 0, 0);
  o1 = __builtin_amdgcn_mfma_f32_16x16x32_bf16(vA1, B0.v, o1, 0, 0, 0);
  o1 = __builtin_amdgcn_mfma_f32_16x16x32_bf16(vB1, B1.v, o1, 0, 0, 0);
  o2 = __builtin_amdgcn_mfma_f32_16x16x32_bf16(vA2, B0.v, o2, 0, 0, 0);
  o2 = __builtin_amdgcn_mfma_f32_16x16x32_bf16(vB2, B1.v, o2, 0, 0, 0);
  o3 = __builtin_amdgcn_mfma_f32_16x16x32_bf16(vA3, B0.v, o3, 0, 0, 0);
  o3 = __builtin_amdgcn_mfma_f32_16x16x32_bf16(vB3, B1.v, o3, 0, 0, 0);
}

// ---------------- causal flash attention: 1-wave blocks, longest-first ----
// grid 4096 x 64 threads. Block = one wave handling one 32-row q-group
// (rows 32s..32s+32, two 16-row halves with SAME k-bound, shared K/V
// fragment loads). No LDS, no barriers; K/V direct from L2 (bh colocated
// per XCD). V tile-blocked (kt,d,ksigma): every V load = 16 cache lines
// (4 lanes/line), same as K.
__global__ __launch_bounds__(64) void flash_attn(
    const bf16_t* __restrict__ Qg, const bf16_t* __restrict__ Kg,
    const bf16_t* __restrict__ VTg, bf16_t* __restrict__ Y)
{
  const int T = 2048, HS = 64;
  const int flat = blockIdx.x;         // 0..4095
  const int xcd = flat & 7;
  const int rest = flat >> 3;          // 0..511
  const int bh = xcd * 8 + (rest & 7); // 8 heads per XCD -> K/V L2-resident
  const int s = 63 - (rest >> 3);      // 32-row q-group, longest first
  const size_t baseQ = (size_t)bh * T * HS;   // Q,K: (bh, t, d)
  const size_t baseV = (size_t)bh * HS * T;   // V: (bh, kt, d, ksigma) tiles

  const int lane = threadIdx.x & 63;
  const int l15 = lane & 15, l4 = lane >> 4;

  const int bound = s >> 1;                 // last k-tile (same for halves)
  const int qb0 = ((s & 1) << 5) + l15;     // q offset within diag 64-tile
  const int qb1 = qb0 + 16;
  const int kb = l4 * 4;

  // Q fragments: half0 rows 32s+l15, half1 rows 32s+16+l15
  const bf16_t* qr = Qg + baseQ + (size_t)(32 * s + l15) * HS;
  const bf16x8 aq00 = *(const bf16x8*)(qr + l4 * 8);
  const bf16x8 aq01 = *(const bf16x8*)(qr + 32 + l4 * 8);
  const bf16x8 aq10 = *(const bf16x8*)(qr + 16 * HS + l4 * 8);
  const bf16x8 aq11 = *(const bf16x8*)(qr + 16 * HS + 32 + l4 * 8);

  float m0 = -1e30f, l0 = 0.f, m1 = -1e30f, l1 = 0.f;
  f32x4 o00 = {}, o01 = {}, o02 = {}, o03 = {};
  f32x4 o10 = {}, o11 = {}, o12 = {}, o13 = {};

  // per-lane fragment bases
  const bf16_t* kp = Kg + baseQ + (size_t)l15 * HS + l4 * 8;   // +4096/kt
  const bf16_t* vp = VTg + baseV + (size_t)l15 * 64 + l4 * 8;  // +4096/kt

  for (int kt = 0; kt <= bound; ++kt) {
    const bool dg = (kt == bound);
    // ---- K fragments (shared by both halves) ----
    const bf16x8 kA0 = *(const bf16x8*)(kp + 0);
    const bf16x8 kB0 = *(const bf16x8*)(kp + 32);
    const bf16x8 kA1 = *(const bf16x8*)(kp + 1024);
    const bf16x8 kB1 = *(const bf16x8*)(kp + 1024 + 32);
    const bf16x8 kA2 = *(const bf16x8*)(kp + 2048);
    const bf16x8 kB2 = *(const bf16x8*)(kp + 2048 + 32);
    const bf16x8 kA3 = *(const bf16x8*)(kp + 3072);
    const bf16x8 kB3 = *(const bf16x8*)(kp + 3072 + 32);
    // ---- V fragments issued early: latency hides under softmax VALU ----
    const bf16x8 vA0 = *(const bf16x8*)(vp + 0);
    const bf16x8 vB0 = *(const bf16x8*)(vp + 32);
    const bf16x8 vA1 = *(const bf16x8*)(vp + 1024);
    const bf16x8 vB1 = *(const bf16x8*)(vp + 1024 + 32);
    const bf16x8 vA2 = *(const bf16x8*)(vp + 2048);
    const bf16x8 vB2 = *(const bf16x8*)(vp + 2048 + 32);
    const bf16x8 vA3 = *(const bf16x8*)(vp + 3072);
    const bf16x8 vB3 = *(const bf16x8*)(vp + 3072 + 32);

    half_step(kA0, kB0, kA1, kB1, kA2, kB2, kA3, kB3,
              vA0, vB0, vA1, vB1, vA2, vB2, vA3, vB3,
              aq00, aq01, m0, l0, o00, o01, o02, o03, dg, qb0, kb);
    half_step(kA0, kB0, kA1, kB1, kA2, kB2, kA3, kB3,
              vA0, vB0, vA1, vB1, vA2, vB2, vA3, vB3,
              aq10, aq11, m1, l1, o10, o11, o12, o13, dg, qb1, kb);

    kp += 4096;
    vp += 4096;
  }

  // epilogue: O^T (d = t*16+l4*4+i, q = l15) -> Y (B,T,C) bf16, packed 8B
  const int b = bh >> 4, h = bh & 15;
  {
    const float il = 1.f / l0;
    const int q = 32 * s + l15;
    bf16_t* yr = Y + ((size_t)(b * T + q)) * 1024 + h * 64 + l4 * 4;
    uint2 w;
    w.x = cvt_pk(o00[0] * il, o00[1] * il); w.y = cvt_pk(o00[2] * il, o00[3] * il);
    *(uint2*)(yr + 0) = w;
    w.x = cvt_pk(o01[0] * il, o01[1] * il); w.y = cvt_pk(o01[2] * il, o01[3] * il);
    *(uint2*)(yr + 16) = w;
    w.x = cvt_pk(o02[0] * il, o02[1] * il); w.y = cvt_pk(o02[2] * il, o02[3] * il);
    *(uint2*)(yr + 32) = w;
    w.x = cvt_pk(o03[0] * il, o03[1] * il); w.y = cvt_pk(o03[2] * il, o03[3] * il);
    *(uint2*)(yr + 48) = w;
  }
  {
    const float il = 1.f / l1;
    const int q = 32 * s + 16 + l15;
    bf16_t* yr = Y + ((size_t)(b * T + q)) * 1024 + h * 64 + l4 * 4;
    uint2 w;
    w.x = cvt_pk(o10[0] * il, o10[1] * il); w.y = cvt_pk(o10[2] * il, o10[3] * il);
    *(uint2*)(yr + 0) = w;
    w.x = cvt_pk(o11[0] * il, o11[1] * il); w.y = cvt_pk(o11[2] * il, o11[3] * il);
    *(uint2*)(yr + 16) = w;
    w.x = cvt_pk(o12[0] * il, o12[1] * il); w.y = cvt_pk(o12[2] * il, o12[3] * il);
    *(uint2*)(yr + 32) = w;
    w.x = cvt_pk(o13[0] * il, o13[1] * il); w.y = cvt_pk(o13[2] * il, o13[3] * il);
    *(uint2*)(yr + 48) = w;
  }
}

// ---------------- launch ----------------
extern "C" void kernel_launch(void* const* d_in, const int* in_sizes, int n_in,
                              void* d_out, int out_size, void* d_ws, size_t ws_size,
                              hipStream_t stream) {
  const float* x      = (const float*)d_in[0];
  const float* w_attn = (const float*)d_in[1];
  const float* b_attn = (const float*)d_in[2];
  const float* w_proj = (const float*)d_in[3];
  const float* b_proj = (const float*)d_in[4];
  float* out = (float*)d_out;

  char* ws = (char*)d_ws;
  bf16_t* xb   = (bf16_t*)(ws);
  bf16_t* wab  = (bf16_t*)(ws + 16777216);
  bf16_t* wpb  = (bf16_t*)(ws + 23068672);
  bf16_t* qkvb = (bf16_t*)(ws + 25165824);   // q | k | vTiles (8M elems each)
  bf16_t* yb   = (bf16_t*)(ws + 75497472);

  cvt_f32_bf16<<<8192, 256, 0, stream>>>(x, xb, 2097152);
  cvt_f32_bf16<<<3072, 256, 0, stream>>>(w_attn, wab, 786432);
  cvt_f32_bf16<<<1024, 256, 0, stream>>>(w_proj, wpb, 262144);

  dim3 g1(24, 64);
  gemm_bt<0><<<g1, 256, 0, stream>>>(xb, wab, b_attn, (void*)qkvb, 8192, 3072, 1024);

  flash_attn<<<4096, 64, 0, stream>>>(qkvb, qkvb + 8388608, qkvb + 16777216, yb);

  dim3 g3(8, 64);
  gemm_bt<1><<<g3, 256, 0, stream>>>(yb, wpb, b_proj, (void*)out, 8192, 1024, 1024);
}